// Round 8
// baseline (332.147 us; speedup 1.0000x reference)
//
#include <hip/hip_runtime.h>
#include <stdint.h>

typedef float f4_t __attribute__((ext_vector_type(4)));
typedef __bf16 bf8_t __attribute__((ext_vector_type(8)));
typedef unsigned short us4_t __attribute__((ext_vector_type(4)));
typedef unsigned short us8_t __attribute__((ext_vector_type(8)));

static __device__ __forceinline__ unsigned short fbf(float f) {
    __bf16 b = (__bf16)f;
    return *(unsigned short*)&b;
}
static __device__ __forceinline__ float bf2f(unsigned short u) {
    union { uint32_t u; float f; } v; v.u = ((uint32_t)u) << 16;
    return v.f;
}
static __device__ __forceinline__ f4_t mfma16(bf8_t a, bf8_t b, f4_t c) {
    return __builtin_amdgcn_mfma_f32_16x16x32_bf16(a, b, c, 0, 0, 0);
}
static __device__ __forceinline__ float sigf(float x) {
    return 1.0f / (1.0f + __expf(-x));
}
static __device__ __forceinline__ void gload_lds16(const void* g, void* l) {
    __builtin_amdgcn_global_load_lds(
        (const __attribute__((address_space(1))) void*)g,
        (__attribute__((address_space(3))) void*)l, 16, 0, 0);
}

// ---------------- kernel 0: convert x/h/W to bf16, build q-normalized x ----
__global__ __launch_bounds__(256) void k_convert(
    const float* __restrict__ x, const float* __restrict__ h,
    const float* __restrict__ W1, const float* __restrict__ W2,
    unsigned short* __restrict__ qn, unsigned short* __restrict__ xb,
    unsigned short* __restrict__ hb, unsigned short* __restrict__ w1b,
    unsigned short* __restrict__ w2b)
{
    __shared__ float sred[4];
    int bid = blockIdx.x, t = threadIdx.x;
    if (bid < 256) {
        float v = x[bid * 256 + t];
        float ss = v * v;
        #pragma unroll
        for (int m = 1; m < 64; m <<= 1) ss += __shfl_xor(ss, m, 64);
        if ((t & 63) == 0) sred[t >> 6] = ss;
        __syncthreads();
        float tot = sred[0] + sred[1] + sred[2] + sred[3];
        float rn = 1.0f / fmaxf(sqrtf(tot), 1e-8f);
        xb[bid * 256 + t] = fbf(v);
        qn[bid * 256 + t] = fbf(v * rn);
    } else if (bid < 512) {
        int b = bid - 256;
        hb[b * 256 + t] = fbf(h[b * 256 + t]);
    } else {
        int i0 = (bid - 512) * 256 + t;
        for (int i = i0; i < 1280 * 256; i += 512 * 256) {
            w1b[i] = fbf(W1[i]);
            w2b[i] = fbf(W2[i]);
        }
    }
}

// ---------------- kernel 1: preact = x@W1^T + h@W2^T + b1 + b2 --------------
__global__ __launch_bounds__(256) void k_gates(
    const unsigned short* __restrict__ xb, const unsigned short* __restrict__ hb,
    const unsigned short* __restrict__ w1b, const unsigned short* __restrict__ w2b,
    const float* __restrict__ b1, const float* __restrict__ b2,
    float* __restrict__ pre)
{
    int bb = (blockIdx.x & 3) * 64;
    int gb = (blockIdx.x >> 2) * 64;
    int t = threadIdx.x, w = t >> 6, lane = t & 63;
    int l15 = lane & 15, q8 = (lane >> 4) * 8, q4 = (lane >> 4) * 4;
    int arow = bb + w * 16 + l15;

    f4_t acc[4] = {};
    #pragma unroll
    for (int ks = 0; ks < 8; ++ks) {
        bf8_t a = *(const bf8_t*)&xb[arow * 256 + ks * 32 + q8];
        #pragma unroll
        for (int gc = 0; gc < 4; ++gc) {
            bf8_t bf = *(const bf8_t*)&w1b[(gb + gc * 16 + l15) * 256 + ks * 32 + q8];
            acc[gc] = mfma16(a, bf, acc[gc]);
        }
    }
    #pragma unroll
    for (int ks = 0; ks < 8; ++ks) {
        bf8_t a = *(const bf8_t*)&hb[arow * 256 + ks * 32 + q8];
        #pragma unroll
        for (int gc = 0; gc < 4; ++gc) {
            bf8_t bf = *(const bf8_t*)&w2b[(gb + gc * 16 + l15) * 256 + ks * 32 + q8];
            acc[gc] = mfma16(a, bf, acc[gc]);
        }
    }
    #pragma unroll
    for (int gc = 0; gc < 4; ++gc) {
        int g = gb + gc * 16 + l15;
        float bias = b1[g] + b2[g];
        #pragma unroll
        for (int r = 0; r < 4; ++r) {
            int b = bb + w * 16 + q4 + r;
            pre[b * 1280 + g] = acc[gc][r] + bias;
        }
    }
}

// ---------------- kernel 2: fused DND memory partials ------------------------
// 512 blocks = 256 chunks x 2 h-halves (twins bid/bid^8 -> same XCD, share K
// via L2). 512 threads, 8 waves; wave w owns b-rows w*32..+31 x 128 h.
// 16-key sub-tiles; raw fp32 staged by async global_load_lds (single-buffered,
// barrier-separated phases); LDS->LDS convert (row-per-wave K reads =
// conflict-free); GEMM2 every 2 sub-tiles (K=32). LDS 62KB -> 2 blocks/CU.
__global__ __launch_bounds__(512, 4) void k_dnd(
    const float* __restrict__ keys, const float* __restrict__ vals,
    const unsigned short* __restrict__ qn,
    unsigned short* __restrict__ opart, float* __restrict__ dpart,
    int L, int CH)
{
    // rawK @0      [16][256] f32   16384B
    // rawV @16384  [16][128] f32    8192B
    // Kb   @24576  [16][256] bf16 XOR-swz  8192B
    // Vb   @32768  [128] rows, stride 80B (32 l bf16 + pad)  10240B
    // P    @43008  [256] rows, stride 80B (32 l bf16 + pad)  20480B
    __shared__ __align__(16) char smem[63488];
    unsigned short* Kb = (unsigned short*)(smem + 24576);

    const int t = threadIdx.x;
    const int w = t >> 6, lane = t & 63;
    const int l15 = lane & 15;
    const int q = lane >> 4, q8 = q * 8, q4 = q * 4;

    const int bid = blockIdx.x;
    const int hhalf = (bid >> 3) & 1;
    const int chunk = (bid & 7) | ((bid >> 4) << 3);
    const int base = chunk * CH;
    int nkeys = L - base;
    if (nkeys > CH) nkeys = CH;
    if (nkeys < 0) nkeys = 0;
    const int nt = (nkeys + 15) >> 4;
    const int nt2 = (nt + 1) & ~1;          // round up to pair

    // Q fragments (qn L2-resident bf16); compiler may refetch under reg cap.
    bf8_t qa[2][8];
    #pragma unroll
    for (int bt = 0; bt < 2; ++bt)
        #pragma unroll
        for (int ks = 0; ks < 8; ++ks)
            qa[bt][ks] = *(const bf8_t*)&qn[(w * 32 + bt * 16 + l15) * 256 + ks * 32 + q8];

    f4_t o[2][8] = {};
    float den[2][4] = {};

    auto issueRaw = [&](int tt) {
        int r0 = base + tt * 16;
        // K: wave w stages local rows 2w, 2w+1 (1KB each, lane*16B linear)
        #pragma unroll
        for (int i = 0; i < 2; ++i) {
            int row = r0 + 2 * w + i;
            if (row >= L) row = L - 1;
            gload_lds16(keys + (size_t)row * 256 + lane * 4,
                        smem + (2 * w + i) * 1024);
        }
        // V: wave w stages local rows 2w,2w+1 of its h-half (2x512B in one call)
        int vrow = r0 + 2 * w + (lane >> 5);
        if (vrow >= L) vrow = L - 1;
        gload_lds16(vals + (size_t)vrow * 256 + hhalf * 128 + (lane & 31) * 4,
                    smem + 16384 + w * 1024);
    };

    auto convert = [&](int tt) {
        // K: wave w handles rows w and w+8; full-row read = conflict-free.
        const float* Kraw = (const float*)smem;
        #pragma unroll
        for (int i = 0; i < 2; ++i) {
            int r = w + i * 8;
            f4_t v = *(const f4_t*)&Kraw[r * 256 + lane * 4];
            float ss = v[0]*v[0] + v[1]*v[1] + v[2]*v[2] + v[3]*v[3];
            #pragma unroll
            for (int m = 1; m < 64; m <<= 1) ss += __shfl_xor(ss, m, 64);
            float rn = 1.0f / fmaxf(sqrtf(ss), 1e-8f);
            us4_t uv;
            uv[0] = fbf(v[0]*rn); uv[1] = fbf(v[1]*rn);
            uv[2] = fbf(v[2]*rn); uv[3] = fbf(v[3]*rn);
            *(us4_t*)&Kb[r * 256 + ((lane * 4) ^ ((r & 7) * 8))] = uv;
        }
        // V transpose: thread -> h = t&127, l-quad lq = t>>7
        const float* Vraw = (const float*)(smem + 16384);
        unsigned short* Vb = (unsigned short*)(smem + 32768);
        int hh = t & 127, lq = t >> 7;
        us4_t uv;
        #pragma unroll
        for (int j = 0; j < 4; ++j)
            uv[j] = fbf(Vraw[(lq * 4 + j) * 128 + hh]);
        *(us4_t*)&Vb[hh * 40 + (tt & 1) * 16 + lq * 4] = uv;
    };

    if (nt2 > 0) {
        issueRaw(0);
        asm volatile("s_waitcnt vmcnt(0)" ::: "memory");
        __builtin_amdgcn_s_barrier();
        convert(0);
        asm volatile("s_waitcnt lgkmcnt(0)\n\ts_barrier" ::: "memory");
        if (nt2 > 1) issueRaw(1);

        for (int tt = 0; tt < nt2; ++tt) {
            // ---- GEMM1: S = Q @ Kn^T (wave: 32 b x 16 l) ----
            f4_t s[2] = {};
            __builtin_amdgcn_s_setprio(1);
            #pragma unroll
            for (int ks = 0; ks < 8; ++ks) {
                bf8_t kf = *(const bf8_t*)&Kb[l15 * 256 + ((ks * 32 + q8) ^ ((l15 & 7) * 8))];
                s[0] = mfma16(qa[0][ks], kf, s[0]);
                s[1] = mfma16(qa[1][ks], kf, s[1]);
            }
            __builtin_amdgcn_s_setprio(0);

            // ---- p = exp(s - 1); den accum; P -> LDS (parity slot) ----
            {
                unsigned short* P = (unsigned short*)(smem + 43008);
                bool valid = (tt * 16 + l15) < nkeys;
                #pragma unroll
                for (int bt = 0; bt < 2; ++bt)
                    #pragma unroll
                    for (int r = 0; r < 4; ++r) {
                        float p = valid ? __expf(s[bt][r] - 1.0f) : 0.0f;
                        den[bt][r] += p;
                        int b = w * 32 + bt * 16 + q4 + r;
                        P[b * 40 + (tt & 1) * 16 + l15] = fbf(p);
                    }
            }

            // ---- GEMM2 every 2 sub-tiles: O += P(pair) @ V(pair), K=32 ----
            if (tt & 1) {
                const unsigned short* P = (const unsigned short*)(smem + 43008);
                const unsigned short* Vb = (const unsigned short*)(smem + 32768);
                bf8_t pa0 = *(const bf8_t*)&P[(w * 32 + l15) * 40 + q8];
                bf8_t pa1 = *(const bf8_t*)&P[(w * 32 + 16 + l15) * 40 + q8];
                __builtin_amdgcn_s_setprio(1);
                #pragma unroll
                for (int hc = 0; hc < 8; ++hc) {
                    int hh = hc * 16 + l15;
                    bf8_t vf = *(const bf8_t*)&Vb[hh * 40 + q8];
                    o[0][hc] = mfma16(pa0, vf, o[0][hc]);
                    o[1][hc] = mfma16(pa1, vf, o[1][hc]);
                }
                __builtin_amdgcn_s_setprio(0);
            }

            // ---- stage: raw(t+1) landed during GEMMs; convert; issue t+2 ----
            if (tt + 1 < nt2) {
                asm volatile("s_waitcnt vmcnt(0)" ::: "memory");
                __builtin_amdgcn_s_barrier();
                convert(tt + 1);
                asm volatile("s_waitcnt lgkmcnt(0)\n\ts_barrier" ::: "memory");
                if (tt + 2 < nt2) issueRaw(tt + 2);
            }
        }
    }

    // ---- epilogue: drain; two-pass LDS transpose -> coalesced stores ----
    asm volatile("s_waitcnt vmcnt(0)" ::: "memory");
    unsigned short* Ol = (unsigned short*)smem;   // [128 b][128 h] per pass
    #pragma unroll
    for (int p = 0; p < 2; ++p) {
        __syncthreads();
        if ((w >> 2) == p) {
            int wl = w & 3;
            #pragma unroll
            for (int bt = 0; bt < 2; ++bt)
                #pragma unroll
                for (int hc = 0; hc < 8; ++hc)
                    #pragma unroll
                    for (int r = 0; r < 4; ++r)
                        Ol[(wl * 32 + bt * 16 + q4 + r) * 128 + hc * 16 + l15] = fbf(o[bt][hc][r]);
        }
        __syncthreads();
        size_t ob = (size_t)(chunk * 2 + hhalf) * 32768 + (size_t)p * 16384;
        #pragma unroll
        for (int it = 0; it < 4; ++it) {
            int off = it * 4096 + t * 8;
            *(us8_t*)&opart[ob + off] = *(const us8_t*)&Ol[off];
        }
    }
    if (hhalf == 0) {
        #pragma unroll
        for (int bt = 0; bt < 2; ++bt)
            #pragma unroll
            for (int r = 0; r < 4; ++r) {
                float d = den[bt][r];
                #pragma unroll
                for (int m = 1; m < 16; m <<= 1) d += __shfl_xor(d, m, 64);
                if (l15 == 0)
                    dpart[chunk * 256 + w * 32 + bt * 16 + q4 + r] = d;
            }
    }
}

// ---------------- kernel 3: reduce partials + LSTM epilogue -----------------
// grid: 256 blocks (one per batch row) x 256 threads (one per h)
__global__ __launch_bounds__(256) void k_reduce(
    const unsigned short* __restrict__ opart, const float* __restrict__ dpart,
    const float* __restrict__ pre, const float* __restrict__ c_in,
    float* __restrict__ out)
{
    __shared__ float sred[4];
    int b = blockIdx.x, t = threadIdx.x;

    float ds = dpart[t * 256 + b];          // t = chunk index, 256 chunks
    #pragma unroll
    for (int m = 1; m < 64; m <<= 1) ds += __shfl_xor(ds, m, 64);
    if ((t & 63) == 0) sred[t >> 6] = ds;
    __syncthreads();
    float dtot = fmaxf(sred[0] + sred[1] + sred[2] + sred[3], 1e-30f);

    int bh = t >> 7, hcol = t & 127;
    size_t sb = (size_t)b * 128 + hcol + (size_t)bh * 32768;
    float n0 = 0.f, n1 = 0.f, n2 = 0.f, n3 = 0.f;
    for (int ck = 0; ck < 256; ck += 4) {
        n0 += bf2f(opart[(size_t)(ck + 0) * 65536 + sb]);
        n1 += bf2f(opart[(size_t)(ck + 1) * 65536 + sb]);
        n2 += bf2f(opart[(size_t)(ck + 2) * 65536 + sb]);
        n3 += bf2f(opart[(size_t)(ck + 3) * 65536 + sb]);
    }
    float num = (n0 + n1) + (n2 + n3);

    float m = tanhf(num / dtot);
    const float* p = pre + b * 1280;
    float fg = sigf(p[t]);
    float ig = sigf(p[256 + t]);
    float og = sigf(p[512 + t]);
    float rg = sigf(p[768 + t]);
    float cn = tanhf(p[1024 + t]);
    float co = c_in[b * 256 + t];
    float ct = fg * co + ig * cn + rg * m;
    float ht = og * tanhf(ct);
    out[b * 256 + t] = ht;
    out[65536 + b * 256 + t] = ct;
}

// ---------------- launch ----------------------------------------------------
extern "C" void kernel_launch(void* const* d_in, const int* in_sizes, int n_in,
                              void* d_out, int out_size, void* d_ws, size_t ws_size,
                              hipStream_t stream)
{
    const float* x    = (const float*)d_in[0];
    const float* h    = (const float*)d_in[1];
    const float* c    = (const float*)d_in[2];
    const float* W1   = (const float*)d_in[3];
    const float* b1   = (const float*)d_in[4];
    const float* W2   = (const float*)d_in[5];
    const float* b2   = (const float*)d_in[6];
    const float* keys = (const float*)d_in[7];
    const float* vals = (const float*)d_in[8];
    int L = in_sizes[7] / 256;

    // 256 chunks, each a multiple of 16 keys
    int TILES = (L + 256 * 16 - 1) / (256 * 16);
    int CH = TILES * 16;

    char* ws = (char*)d_ws;
    unsigned short* qn    = (unsigned short*)(ws + 0);
    unsigned short* xb    = (unsigned short*)(ws + 131072);
    unsigned short* hb    = (unsigned short*)(ws + 262144);
    unsigned short* w1b   = (unsigned short*)(ws + 393216);
    unsigned short* w2b   = (unsigned short*)(ws + 1048576);
    float*          pre   = (float*)(ws + 1703936);
    float*          dpart = (float*)(ws + 3014656);   // 256*256 f32 = 256KB
    unsigned short* opart = (unsigned short*)(ws + 3276800);

    k_convert<<<dim3(1024), dim3(256), 0, stream>>>(x, h, W1, W2, qn, xb, hb, w1b, w2b);
    k_gates<<<dim3(80), dim3(256), 0, stream>>>(xb, hb, w1b, w2b, b1, b2, pre);
    k_dnd<<<dim3(512), dim3(512), 0, stream>>>(keys, vals, qn, opart, dpart, L, CH);
    k_reduce<<<dim3(256), dim3(256), 0, stream>>>(opart, dpart, pre, c, (float*)d_out);

    (void)n_in; (void)out_size; (void)ws_size;
}

// Round 9
// 168.567 us; speedup vs baseline: 1.9704x; 1.9704x over previous
//
#include <hip/hip_runtime.h>
#include <stdint.h>

typedef float f4_t __attribute__((ext_vector_type(4)));
typedef float f16_t __attribute__((ext_vector_type(16)));
typedef __bf16 bf8_t __attribute__((ext_vector_type(8)));
typedef unsigned short us4_t __attribute__((ext_vector_type(4)));
typedef unsigned short us8_t __attribute__((ext_vector_type(8)));

static __device__ __forceinline__ unsigned short fbf(float f) {
    __bf16 b = (__bf16)f;
    return *(unsigned short*)&b;
}
static __device__ __forceinline__ float bf2f(unsigned short u) {
    union { uint32_t u; float f; } v; v.u = ((uint32_t)u) << 16;
    return v.f;
}
static __device__ __forceinline__ f4_t mfma16(bf8_t a, bf8_t b, f4_t c) {
    return __builtin_amdgcn_mfma_f32_16x16x32_bf16(a, b, c, 0, 0, 0);
}
static __device__ __forceinline__ f16_t mfma32(bf8_t a, bf8_t b, f16_t c) {
    return __builtin_amdgcn_mfma_f32_32x32x16_bf16(a, b, c, 0, 0, 0);
}
static __device__ __forceinline__ float sigf(float x) {
    return 1.0f / (1.0f + __expf(-x));
}
static __device__ __forceinline__ void gload_lds16(const void* g, void* l) {
    __builtin_amdgcn_global_load_lds(
        (const __attribute__((address_space(1))) void*)g,
        (__attribute__((address_space(3))) void*)l, 16, 0, 0);
}
static __device__ __forceinline__ uint32_t cvtpk(float lo, float hi) {
    uint32_t r;
    asm("v_cvt_pk_bf16_f32 %0, %1, %2" : "=v"(r) : "v"(lo), "v"(hi));
    return r;
}

// ---------------- kernel 0: convert x/h/W to bf16, build q-normalized x ----
__global__ __launch_bounds__(256) void k_convert(
    const float* __restrict__ x, const float* __restrict__ h,
    const float* __restrict__ W1, const float* __restrict__ W2,
    unsigned short* __restrict__ qn, unsigned short* __restrict__ xb,
    unsigned short* __restrict__ hb, unsigned short* __restrict__ w1b,
    unsigned short* __restrict__ w2b)
{
    __shared__ float sred[4];
    int bid = blockIdx.x, t = threadIdx.x;
    if (bid < 256) {
        float v = x[bid * 256 + t];
        float ss = v * v;
        #pragma unroll
        for (int m = 1; m < 64; m <<= 1) ss += __shfl_xor(ss, m, 64);
        if ((t & 63) == 0) sred[t >> 6] = ss;
        __syncthreads();
        float tot = sred[0] + sred[1] + sred[2] + sred[3];
        float rn = 1.0f / fmaxf(sqrtf(tot), 1e-8f);
        xb[bid * 256 + t] = fbf(v);
        qn[bid * 256 + t] = fbf(v * rn);
    } else if (bid < 512) {
        int b = bid - 256;
        hb[b * 256 + t] = fbf(h[b * 256 + t]);
    } else {
        int i0 = (bid - 512) * 256 + t;
        for (int i = i0; i < 1280 * 256; i += 512 * 256) {
            w1b[i] = fbf(W1[i]);
            w2b[i] = fbf(W2[i]);
        }
    }
}

// ---------------- kernel 1: preact = x@W1^T + h@W2^T + b1 + b2 --------------
__global__ __launch_bounds__(256) void k_gates(
    const unsigned short* __restrict__ xb, const unsigned short* __restrict__ hb,
    const unsigned short* __restrict__ w1b, const unsigned short* __restrict__ w2b,
    const float* __restrict__ b1, const float* __restrict__ b2,
    float* __restrict__ pre)
{
    int bb = (blockIdx.x & 3) * 64;
    int gb = (blockIdx.x >> 2) * 64;
    int t = threadIdx.x, w = t >> 6, lane = t & 63;
    int l15 = lane & 15, q8 = (lane >> 4) * 8, q4 = (lane >> 4) * 4;
    int arow = bb + w * 16 + l15;

    f4_t acc[4] = {};
    #pragma unroll
    for (int ks = 0; ks < 8; ++ks) {
        bf8_t a = *(const bf8_t*)&xb[arow * 256 + ks * 32 + q8];
        #pragma unroll
        for (int gc = 0; gc < 4; ++gc) {
            bf8_t bf = *(const bf8_t*)&w1b[(gb + gc * 16 + l15) * 256 + ks * 32 + q8];
            acc[gc] = mfma16(a, bf, acc[gc]);
        }
    }
    #pragma unroll
    for (int ks = 0; ks < 8; ++ks) {
        bf8_t a = *(const bf8_t*)&hb[arow * 256 + ks * 32 + q8];
        #pragma unroll
        for (int gc = 0; gc < 4; ++gc) {
            bf8_t bf = *(const bf8_t*)&w2b[(gb + gc * 16 + l15) * 256 + ks * 32 + q8];
            acc[gc] = mfma16(a, bf, acc[gc]);
        }
    }
    #pragma unroll
    for (int gc = 0; gc < 4; ++gc) {
        int g = gb + gc * 16 + l15;
        float bias = b1[g] + b2[g];
        #pragma unroll
        for (int r = 0; r < 4; ++r) {
            int b = bb + w * 16 + q4 + r;
            pre[b * 1280 + g] = acc[gc][r] + bias;
        }
    }
}

// ---------------- kernel 2: fused DND memory partials ------------------------
// 1024 blocks = 256 chunks x 4 variants (2 b-halves x 2 h-halves); all 4
// variants of a chunk on the same XCD (bid&7) -> K/V L2-shared. 256 threads,
// 4 waves; wave w owns b-rows (bhalf*128 + w*32..+31) x 128 h (its half).
// 32-key tiles; raw fp32 staged via async global_load_lds, LDS->LDS convert
// (bank-floor patterns). GEMM1 SWAPPED (mfma32(K,Q) -> S[l][b], b=lane&31);
// softmax P rebuilt into GEMM2 A-frags IN REGISTERS via cvt_pk_bf16 +
// v_permlane32_swap (no P LDS). 74KB LDS + launch_bounds(256,2) -> 2 blk/CU.
__global__ __launch_bounds__(256, 2) void k_dnd(
    const float* __restrict__ keys, const float* __restrict__ vals,
    const unsigned short* __restrict__ qn,
    unsigned short* __restrict__ opart, float* __restrict__ dpart,
    int L, int CH)
{
    // rawK @0 (32KB f32[32][256]) | rawV @32768 (16KB f32[32][128])
    // Kb @49152 (16KB bf16[32][256], byte^=(l&7)*16) | Vb @65536 ([128]x40el)
    __shared__ __align__(16) char smem[75776];

    const int t = threadIdx.x;
    const int w = t >> 6, lane = t & 63;
    const int l31 = lane & 31, hi = lane >> 5;

    const int bid = blockIdx.x;
    const int xcd = bid & 7, sl = bid >> 3;
    const int var = sl & 3;
    const int hhalf = var & 1, bhalf = var >> 1;
    const int chunk = (sl >> 2) * 8 + xcd;
    const int base = chunk * CH;
    int nk = L - base;
    if (nk > CH) nk = CH;
    if (nk < 0) nk = 0;
    const int nt = (nk + 31) >> 5;

    // Q fragments: B-operand of swapped GEMM1 (col b = lane&31, k-slice d)
    bf8_t qf[16];
    #pragma unroll
    for (int st = 0; st < 16; ++st)
        qf[st] = *(const bf8_t*)&qn[(bhalf * 128 + w * 32 + l31) * 256 + st * 16 + hi * 8];

    f16_t o[4] = {};
    float den = 0.f;

    auto issueRaw = [&](int tt) {
        int r0 = base + tt * 32;
        #pragma unroll
        for (int i = 0; i < 8; ++i) {
            int row = r0 + w * 8 + i;
            if (row >= L) row = L - 1;
            gload_lds16(keys + (size_t)row * 256 + lane * 4, smem + (w * 8 + i) * 1024);
        }
        #pragma unroll
        for (int j = 0; j < 4; ++j) {
            int rr = w * 8 + 2 * j;
            int row = r0 + rr + hi;
            if (row >= L) row = L - 1;
            gload_lds16(vals + (size_t)row * 256 + hhalf * 128 + l31 * 4,
                        smem + 32768 + rr * 512);
        }
    };

    auto convert = [&]() {
        // K: one row per wave-iter (full-row b128 read = bank floor), wave
        // shfl norm-reduce, bf16, XOR-swizzled write (lane-permuted = floor).
        const float* rawK = (const float*)smem;
        unsigned short* Kb = (unsigned short*)(smem + 49152);
        #pragma unroll
        for (int i = 0; i < 8; ++i) {
            int r = w * 8 + i;
            f4_t x = *(const f4_t*)&rawK[r * 256 + lane * 4];
            float ss = x[0]*x[0] + x[1]*x[1] + x[2]*x[2] + x[3]*x[3];
            #pragma unroll
            for (int m = 1; m < 64; m <<= 1) ss += __shfl_xor(ss, m, 64);
            float rn = 1.0f / fmaxf(sqrtf(ss), 1e-8f);
            us4_t uv;
            uv[0] = fbf(x[0]*rn); uv[1] = fbf(x[1]*rn);
            uv[2] = fbf(x[2]*rn); uv[3] = fbf(x[3]*rn);
            *(us4_t*)((char*)Kb + r * 512 + ((lane * 8) ^ ((r & 7) * 16))) = uv;
        }
        // V transpose: thread -> h = t&127, l-half = t>>7 (b32 reads, 2-way)
        const float* rawV = (const float*)(smem + 32768);
        unsigned short* Vb = (unsigned short*)(smem + 65536);
        int hh = t & 127, lh = t >> 7;
        us8_t a, b;
        #pragma unroll
        for (int j = 0; j < 8; ++j) a[j] = fbf(rawV[(lh * 16 + j) * 128 + hh]);
        #pragma unroll
        for (int j = 0; j < 8; ++j) b[j] = fbf(rawV[(lh * 16 + 8 + j) * 128 + hh]);
        *(us8_t*)&Vb[hh * 40 + lh * 16] = a;
        *(us8_t*)&Vb[hh * 40 + lh * 16 + 8] = b;
    };

    const unsigned short* Kb = (const unsigned short*)(smem + 49152);
    const unsigned short* Vb = (const unsigned short*)(smem + 65536);

    if (nt > 0) {
        issueRaw(0);
        asm volatile("s_waitcnt vmcnt(0)" ::: "memory");
        __builtin_amdgcn_s_barrier();
        convert();
        asm volatile("s_waitcnt lgkmcnt(0)\n\ts_barrier" ::: "memory");

        for (int tt = 0; tt < nt; ++tt) {
            if (tt + 1 < nt) issueRaw(tt + 1);

            // ---- GEMM1 (swapped): S[l][b] = K @ Q^T, 16 d-steps ----
            f16_t sc = {};
            __builtin_amdgcn_s_setprio(1);
            #pragma unroll
            for (int st = 0; st < 16; ++st) {
                bf8_t kf = *(const bf8_t*)((const char*)Kb + l31 * 512 +
                               ((st * 32 + hi * 16) ^ ((l31 & 7) * 16)));
                sc = mfma32(kf, qf[st], sc);
            }
            __builtin_amdgcn_s_setprio(0);

            // ---- softmax in-register: p = exp(s-1), den accum ----
            float p[16];
            bool full = (tt * 32 + 32 <= nk);
            #pragma unroll
            for (int r = 0; r < 16; ++r) {
                int l = (r & 3) + 8 * (r >> 2) + 4 * hi;
                float pv = __expf(sc[r] - 1.0f);
                if (!full && (tt * 32 + l) >= nk) pv = 0.f;
                p[r] = pv;
                den += pv;
            }
            // pack to GEMM2 A-frags via cvt_pk + permlane32_swap (T12)
            uint32_t a0 = cvtpk(p[0], p[1]),   a1 = cvtpk(p[2], p[3]);
            uint32_t b0 = cvtpk(p[4], p[5]),   b1 = cvtpk(p[6], p[7]);
            uint32_t c0 = cvtpk(p[8], p[9]),   c1 = cvtpk(p[10], p[11]);
            uint32_t d0 = cvtpk(p[12], p[13]), d1 = cvtpk(p[14], p[15]);
            asm("v_permlane32_swap_b32 %0, %1" : "+v"(a0), "+v"(b0));
            asm("v_permlane32_swap_b32 %0, %1" : "+v"(a1), "+v"(b1));
            asm("v_permlane32_swap_b32 %0, %1" : "+v"(c0), "+v"(d0));
            asm("v_permlane32_swap_b32 %0, %1" : "+v"(c1), "+v"(d1));
            union { uint32_t u[4]; bf8_t v; } pa0, pa1;
            pa0.u[0] = a0; pa0.u[1] = a1; pa0.u[2] = b0; pa0.u[3] = b1;
            pa1.u[0] = c0; pa1.u[1] = c1; pa1.u[2] = d0; pa1.u[3] = d1;

            // ---- GEMM2: O[b][h] += P @ V, 2 k-steps x 4 h-groups ----
            __builtin_amdgcn_s_setprio(1);
            #pragma unroll
            for (int g = 0; g < 4; ++g) {
                bf8_t vf0 = *(const bf8_t*)&Vb[(g * 32 + l31) * 40 + hi * 8];
                bf8_t vf1 = *(const bf8_t*)&Vb[(g * 32 + l31) * 40 + 16 + hi * 8];
                o[g] = mfma32(pa0.v, vf0, o[g]);
                o[g] = mfma32(pa1.v, vf1, o[g]);
            }
            __builtin_amdgcn_s_setprio(0);

            if (tt + 1 < nt) {
                asm volatile("s_waitcnt vmcnt(0)" ::: "memory");
                __builtin_amdgcn_s_barrier();
                convert();
                asm volatile("s_waitcnt lgkmcnt(0)\n\ts_barrier" ::: "memory");
            }
        }
    }

    // ---- epilogue: LDS transpose -> coalesced stores; den wave-combine ----
    asm volatile("s_waitcnt vmcnt(0)" ::: "memory");
    __syncthreads();
    unsigned short* Ol = (unsigned short*)smem;   // [128 b][128 h]
    #pragma unroll
    for (int g = 0; g < 4; ++g)
        #pragma unroll
        for (int r = 0; r < 16; ++r) {
            int b = w * 32 + (r & 3) + 8 * (r >> 2) + 4 * hi;
            Ol[b * 128 + g * 32 + l31] = fbf(o[g][r]);
        }
    __syncthreads();
    {
        size_t ob = (size_t)((chunk * 2 + bhalf) * 2 + hhalf) * 16384;
        #pragma unroll
        for (int it = 0; it < 8; ++it) {
            int off = it * 2048 + t * 8;
            *(us8_t*)&opart[ob + off] = *(const us8_t*)&Ol[off];
        }
    }
    den += __shfl_xor(den, 32, 64);
    if (hi == 0 && hhalf == 0)
        dpart[chunk * 256 + bhalf * 128 + w * 32 + l31] = den;
}

// ---------------- kernel 3: reduce partials + LSTM epilogue -----------------
__global__ __launch_bounds__(256) void k_reduce(
    const unsigned short* __restrict__ opart, const float* __restrict__ dpart,
    const float* __restrict__ pre, const float* __restrict__ c_in,
    float* __restrict__ out)
{
    __shared__ float sred[4];
    int b = blockIdx.x, t = threadIdx.x;

    float ds = dpart[t * 256 + b];
    #pragma unroll
    for (int m = 1; m < 64; m <<= 1) ds += __shfl_xor(ds, m, 64);
    if ((t & 63) == 0) sred[t >> 6] = ds;
    __syncthreads();
    float dtot = fmaxf(sred[0] + sred[1] + sred[2] + sred[3], 1e-30f);

    int bh = b >> 7, br = b & 127;
    int hh = t >> 7, hc = t & 127;
    size_t sb = (size_t)(bh * 2 + hh) * 16384 + br * 128 + hc;
    float n0 = 0.f, n1 = 0.f, n2 = 0.f, n3 = 0.f;
    for (int ck = 0; ck < 256; ck += 4) {
        n0 += bf2f(opart[(size_t)(ck + 0) * 65536 + sb]);
        n1 += bf2f(opart[(size_t)(ck + 1) * 65536 + sb]);
        n2 += bf2f(opart[(size_t)(ck + 2) * 65536 + sb]);
        n3 += bf2f(opart[(size_t)(ck + 3) * 65536 + sb]);
    }
    float num = (n0 + n1) + (n2 + n3);

    float m = tanhf(num / dtot);
    const float* p = pre + b * 1280;
    float fg = sigf(p[t]);
    float ig = sigf(p[256 + t]);
    float og = sigf(p[512 + t]);
    float rg = sigf(p[768 + t]);
    float cn = tanhf(p[1024 + t]);
    float co = c_in[b * 256 + t];
    float ct = fg * co + ig * cn + rg * m;
    float ht = og * tanhf(ct);
    out[b * 256 + t] = ht;
    out[65536 + b * 256 + t] = ct;
}

// ---------------- launch ----------------------------------------------------
extern "C" void kernel_launch(void* const* d_in, const int* in_sizes, int n_in,
                              void* d_out, int out_size, void* d_ws, size_t ws_size,
                              hipStream_t stream)
{
    const float* x    = (const float*)d_in[0];
    const float* h    = (const float*)d_in[1];
    const float* c    = (const float*)d_in[2];
    const float* W1   = (const float*)d_in[3];
    const float* b1   = (const float*)d_in[4];
    const float* W2   = (const float*)d_in[5];
    const float* b2   = (const float*)d_in[6];
    const float* keys = (const float*)d_in[7];
    const float* vals = (const float*)d_in[8];
    int L = in_sizes[7] / 256;

    // 256 chunks, each a multiple of 32 keys
    int TILES = (L + 256 * 32 - 1) / (256 * 32);
    int CH = TILES * 32;

    char* ws = (char*)d_ws;
    unsigned short* qn    = (unsigned short*)(ws + 0);
    unsigned short* xb    = (unsigned short*)(ws + 131072);
    unsigned short* hb    = (unsigned short*)(ws + 262144);
    unsigned short* w1b   = (unsigned short*)(ws + 393216);
    unsigned short* w2b   = (unsigned short*)(ws + 1048576);
    float*          pre   = (float*)(ws + 1703936);
    float*          dpart = (float*)(ws + 3014656);   // 256*256 f32 = 256KB
    unsigned short* opart = (unsigned short*)(ws + 3276800);  // 1024*16384*2B

    k_convert<<<dim3(1024), dim3(256), 0, stream>>>(x, h, W1, W2, qn, xb, hb, w1b, w2b);
    k_gates<<<dim3(80), dim3(256), 0, stream>>>(xb, hb, w1b, w2b, b1, b2, pre);
    k_dnd<<<dim3(1024), dim3(256), 0, stream>>>(keys, vals, qn, opart, dpart, L, CH);
    k_reduce<<<dim3(256), dim3(256), 0, stream>>>(opart, dpart, pre, c, (float*)d_out);

    (void)n_in; (void)out_size; (void)ws_size;
}

// Round 10
// 119.264 us; speedup vs baseline: 2.7850x; 1.4134x over previous
//
#include <hip/hip_runtime.h>
#include <stdint.h>

typedef float f4_t __attribute__((ext_vector_type(4)));
typedef float f16_t __attribute__((ext_vector_type(16)));
typedef __bf16 bf8_t __attribute__((ext_vector_type(8)));
typedef unsigned short us4_t __attribute__((ext_vector_type(4)));
typedef unsigned short us8_t __attribute__((ext_vector_type(8)));

static __device__ __forceinline__ unsigned short fbf(float f) {
    __bf16 b = (__bf16)f;
    return *(unsigned short*)&b;
}
static __device__ __forceinline__ float bf2f(unsigned short u) {
    union { uint32_t u; float f; } v; v.u = ((uint32_t)u) << 16;
    return v.f;
}
static __device__ __forceinline__ f4_t mfma16(bf8_t a, bf8_t b, f4_t c) {
    return __builtin_amdgcn_mfma_f32_16x16x32_bf16(a, b, c, 0, 0, 0);
}
static __device__ __forceinline__ f16_t mfma32(bf8_t a, bf8_t b, f16_t c) {
    return __builtin_amdgcn_mfma_f32_32x32x16_bf16(a, b, c, 0, 0, 0);
}
static __device__ __forceinline__ float sigf(float x) {
    return 1.0f / (1.0f + __expf(-x));
}
static __device__ __forceinline__ void gload_lds16(const void* g, void* l) {
    __builtin_amdgcn_global_load_lds(
        (const __attribute__((address_space(1))) void*)g,
        (__attribute__((address_space(3))) void*)l, 16, 0, 0);
}
static __device__ __forceinline__ uint32_t cvtpk(float lo, float hi) {
    uint32_t r;
    asm("v_cvt_pk_bf16_f32 %0, %1, %2" : "=v"(r) : "v"(lo), "v"(hi));
    return r;
}

// ---------------- kernel 0: convert x/h/W to bf16, build q-normalized x ----
__global__ __launch_bounds__(256) void k_convert(
    const float* __restrict__ x, const float* __restrict__ h,
    const float* __restrict__ W1, const float* __restrict__ W2,
    unsigned short* __restrict__ qn, unsigned short* __restrict__ xb,
    unsigned short* __restrict__ hb, unsigned short* __restrict__ w1b,
    unsigned short* __restrict__ w2b)
{
    __shared__ float sred[4];
    int bid = blockIdx.x, t = threadIdx.x;
    if (bid < 256) {
        float v = x[bid * 256 + t];
        float ss = v * v;
        #pragma unroll
        for (int m = 1; m < 64; m <<= 1) ss += __shfl_xor(ss, m, 64);
        if ((t & 63) == 0) sred[t >> 6] = ss;
        __syncthreads();
        float tot = sred[0] + sred[1] + sred[2] + sred[3];
        float rn = 1.0f / fmaxf(sqrtf(tot), 1e-8f);
        xb[bid * 256 + t] = fbf(v);
        qn[bid * 256 + t] = fbf(v * rn);
    } else if (bid < 512) {
        int b = bid - 256;
        hb[b * 256 + t] = fbf(h[b * 256 + t]);
    } else {
        int i0 = (bid - 512) * 256 + t;
        for (int i = i0; i < 1280 * 256; i += 512 * 256) {
            w1b[i] = fbf(W1[i]);
            w2b[i] = fbf(W2[i]);
        }
    }
}

// ---------------- kernel 1: preact = x@W1^T + h@W2^T + b1 + b2 --------------
__global__ __launch_bounds__(256) void k_gates(
    const unsigned short* __restrict__ xb, const unsigned short* __restrict__ hb,
    const unsigned short* __restrict__ w1b, const unsigned short* __restrict__ w2b,
    const float* __restrict__ b1, const float* __restrict__ b2,
    float* __restrict__ pre)
{
    int bb = (blockIdx.x & 3) * 64;
    int gb = (blockIdx.x >> 2) * 64;
    int t = threadIdx.x, w = t >> 6, lane = t & 63;
    int l15 = lane & 15, q8 = (lane >> 4) * 8, q4 = (lane >> 4) * 4;
    int arow = bb + w * 16 + l15;

    f4_t acc[4] = {};
    #pragma unroll
    for (int ks = 0; ks < 8; ++ks) {
        bf8_t a = *(const bf8_t*)&xb[arow * 256 + ks * 32 + q8];
        #pragma unroll
        for (int gc = 0; gc < 4; ++gc) {
            bf8_t bf = *(const bf8_t*)&w1b[(gb + gc * 16 + l15) * 256 + ks * 32 + q8];
            acc[gc] = mfma16(a, bf, acc[gc]);
        }
    }
    #pragma unroll
    for (int ks = 0; ks < 8; ++ks) {
        bf8_t a = *(const bf8_t*)&hb[arow * 256 + ks * 32 + q8];
        #pragma unroll
        for (int gc = 0; gc < 4; ++gc) {
            bf8_t bf = *(const bf8_t*)&w2b[(gb + gc * 16 + l15) * 256 + ks * 32 + q8];
            acc[gc] = mfma16(a, bf, acc[gc]);
        }
    }
    #pragma unroll
    for (int gc = 0; gc < 4; ++gc) {
        int g = gb + gc * 16 + l15;
        float bias = b1[g] + b2[g];
        #pragma unroll
        for (int r = 0; r < 4; ++r) {
            int b = bb + w * 16 + q4 + r;
            pre[b * 1280 + g] = acc[gc][r] + bias;
        }
    }
}

// ---------------- kernel 2: fused DND memory partials ------------------------
// 1024 blocks = 256 chunks x 4 variants (2 b-halves x 2 h-halves), variants
// of a chunk on the same XCD (bid&7) -> K/V shared via L2. 256 threads, 4
// waves; wave w owns b-rows (bhalf*128 + w*32..+31) x 128 h (its half).
// 32-key tiles; raw fp32 via async global_load_lds, WAVE-ALIGNED rows
// (wave w stages AND converts raw rows 8w..8w+7 -> single raw buffer, no
// races). Convert: 8thr/row norm (3 shfls), padded rawK rows (1040B) = all
// LDS at bank floor. GEMM1 swapped mfma32, T12 in-reg P. 74.5KB LDS ->
// 2 blocks/CU (8 waves/CU, the register ceiling for qf+o ~ 180 regs).
__global__ __launch_bounds__(256, 2) void k_dnd(
    const float* __restrict__ keys, const float* __restrict__ vals,
    const unsigned short* __restrict__ qn,
    unsigned short* __restrict__ opart, float* __restrict__ dpart,
    int L, int CH)
{
    // rawK @0      : 32 rows x 1040B = 33280   (padded -> convert at floor)
    // rawV @33280  : 32 rows x 512B  = 16384
    // Kb   @49664  : [32][256] bf16, 16B-XOR swz = 16384
    // Vb   @66048  : [128] rows x 40 el bf16 = 10240
    __shared__ __align__(16) char smem[76288];

    const int t = threadIdx.x;
    const int w = t >> 6, lane = t & 63;
    const int l31 = lane & 31, hi = lane >> 5;

    const int bid = blockIdx.x;
    const int xcd = bid & 7, sl = bid >> 3;
    const int var = sl & 3;
    const int hhalf = var & 1, bhalf = var >> 1;
    const int chunk = (sl >> 2) * 8 + xcd;
    const int base = chunk * CH;
    int nk = L - base;
    if (nk > CH) nk = CH;
    if (nk < 0) nk = 0;
    const int nt = (nk + 31) >> 5;

    // Q fragments: B-operand of swapped GEMM1 (col b = lane&31)
    bf8_t qf[16];
    #pragma unroll
    for (int st = 0; st < 16; ++st)
        qf[st] = *(const bf8_t*)&qn[(bhalf * 128 + w * 32 + l31) * 256 + st * 16 + hi * 8];

    f16_t o[4] = {};
    float den = 0.f;

    // wave w stages raw rows 8w..8w+7 (K: 8 calls, V: 4 calls of 2 rows)
    auto issueRaw = [&](int tt) {
        int r0 = base + tt * 32;
        #pragma unroll
        for (int i = 0; i < 8; ++i) {
            int lr = 8 * w + i;
            int row = r0 + lr;
            if (row >= L) row = L - 1;
            gload_lds16(keys + (size_t)row * 256 + lane * 4, smem + lr * 1040);
        }
        #pragma unroll
        for (int j = 0; j < 4; ++j) {
            int lr = 8 * w + 2 * j;
            int row = r0 + lr + hi;   // lane>>5 picks row lr / lr+1
            if (row >= L) row = L - 1;
            gload_lds16(vals + (size_t)row * 256 + hhalf * 128 + l31 * 4,
                        smem + 33280 + lr * 512);
        }
    };

    // wave-aligned convert: K rows t>>3 (= wave's own), V rows 8w..8w+7
    auto convert = [&]() {
        {
            const int r = t >> 3, j = t & 7;     // 8 threads per K row
            const char* rk = smem + r * 1040;
            f4_t x[8];
            #pragma unroll
            for (int k = 0; k < 8; ++k)
                x[k] = *(const f4_t*)(rk + j * 128 + k * 16);
            float ss = 0.f;
            #pragma unroll
            for (int k = 0; k < 8; ++k)
                ss += x[k][0]*x[k][0] + x[k][1]*x[k][1]
                    + x[k][2]*x[k][2] + x[k][3]*x[k][3];
            ss += __shfl_xor(ss, 1, 64);
            ss += __shfl_xor(ss, 2, 64);
            ss += __shfl_xor(ss, 4, 64);
            float rn = 1.0f / fmaxf(sqrtf(ss), 1e-8f);
            unsigned short* Kb = (unsigned short*)(smem + 49664);
            #pragma unroll
            for (int kk = 0; kk < 4; ++kk) {
                us8_t uv;
                #pragma unroll
                for (int e = 0; e < 4; ++e) {
                    uv[e]     = fbf(x[2*kk][e] * rn);
                    uv[e + 4] = fbf(x[2*kk + 1][e] * rn);
                }
                int col = j * 64 + kk * 16;      // byte col within 512B row
                *(us8_t*)((char*)Kb + r * 512 + (col ^ ((r & 7) * 16))) = uv;
            }
        }
        {
            const float* rv = (const float*)(smem + 33280);
            unsigned short* Vb = (unsigned short*)(smem + 66048);
            #pragma unroll
            for (int hh2 = 0; hh2 < 2; ++hh2) {
                int hh = lane + hh2 * 64;
                us8_t uv;
                #pragma unroll
                for (int i = 0; i < 8; ++i)
                    uv[i] = fbf(rv[(8 * w + i) * 128 + hh]);
                *(us8_t*)&Vb[hh * 40 + 8 * w] = uv;
            }
        }
    };

    const unsigned short* Kb = (const unsigned short*)(smem + 49664);
    const unsigned short* Vb = (const unsigned short*)(smem + 66048);

    if (nt > 0) {
        issueRaw(0);
        asm volatile("s_waitcnt vmcnt(0)" ::: "memory");
        convert();                                 // own rows only: no barrier
        if (nt > 1) issueRaw(1);
        asm volatile("s_waitcnt lgkmcnt(0)\n\ts_barrier" ::: "memory");

        for (int tt = 0; tt < nt; ++tt) {
            // ---- GEMM1 (swapped): S[l][b] = K @ Q^T, 16 d-steps ----
            f16_t sc = {};
            __builtin_amdgcn_s_setprio(1);
            #pragma unroll
            for (int st = 0; st < 16; ++st) {
                bf8_t kf = *(const bf8_t*)((const char*)Kb + l31 * 512 +
                               ((st * 32 + hi * 16) ^ ((l31 & 7) * 16)));
                sc = mfma32(kf, qf[st], sc);
            }
            __builtin_amdgcn_s_setprio(0);

            // ---- softmax in-register: p = exp(s-1), den accum ----
            float p[16];
            bool full = (tt * 32 + 32 <= nk);
            #pragma unroll
            for (int r = 0; r < 16; ++r) {
                int l = (r & 3) + 8 * (r >> 2) + 4 * hi;
                float pv = __expf(sc[r] - 1.0f);
                if (!full && (tt * 32 + l) >= nk) pv = 0.f;
                p[r] = pv;
                den += pv;
            }
            uint32_t a0 = cvtpk(p[0], p[1]),   a1 = cvtpk(p[2], p[3]);
            uint32_t b0 = cvtpk(p[4], p[5]),   b1 = cvtpk(p[6], p[7]);
            uint32_t c0 = cvtpk(p[8], p[9]),   c1 = cvtpk(p[10], p[11]);
            uint32_t d0 = cvtpk(p[12], p[13]), d1 = cvtpk(p[14], p[15]);
            asm("v_permlane32_swap_b32 %0, %1" : "+v"(a0), "+v"(b0));
            asm("v_permlane32_swap_b32 %0, %1" : "+v"(a1), "+v"(b1));
            asm("v_permlane32_swap_b32 %0, %1" : "+v"(c0), "+v"(d0));
            asm("v_permlane32_swap_b32 %0, %1" : "+v"(c1), "+v"(d1));
            union { uint32_t u[4]; bf8_t v; } pa0, pa1;
            pa0.u[0] = a0; pa0.u[1] = a1; pa0.u[2] = b0; pa0.u[3] = b1;
            pa1.u[0] = c0; pa1.u[1] = c1; pa1.u[2] = d0; pa1.u[3] = d1;

            // ---- GEMM2: O[b][h] += P @ V ----
            __builtin_amdgcn_s_setprio(1);
            #pragma unroll
            for (int g = 0; g < 4; ++g) {
                bf8_t vf0 = *(const bf8_t*)&Vb[(g * 32 + l31) * 40 + hi * 8];
                bf8_t vf1 = *(const bf8_t*)&Vb[(g * 32 + l31) * 40 + 16 + hi * 8];
                o[g] = mfma32(pa0.v, vf0, o[g]);
                o[g] = mfma32(pa1.v, vf1, o[g]);
            }
            __builtin_amdgcn_s_setprio(0);

            // ---- stage tile t+1 (landed during GEMMs); issue t+2 ----
            if (tt + 1 < nt) {
                asm volatile("s_waitcnt vmcnt(0)" ::: "memory");
                __builtin_amdgcn_s_barrier();      // Kb/Vb readers done
                convert();
                if (tt + 2 < nt) issueRaw(tt + 2); // own raw rows, just freed
                asm volatile("s_waitcnt lgkmcnt(0)\n\ts_barrier" ::: "memory");
            }
        }
    }

    // ---- epilogue: LDS transpose -> coalesced stores; den combine ----
    asm volatile("s_waitcnt vmcnt(0)" ::: "memory");
    __syncthreads();
    unsigned short* Ol = (unsigned short*)smem;   // [128 b][128 h]
    #pragma unroll
    for (int g = 0; g < 4; ++g)
        #pragma unroll
        for (int r = 0; r < 16; ++r) {
            int b = w * 32 + (r & 3) + 8 * (r >> 2) + 4 * hi;
            Ol[b * 128 + g * 32 + l31] = fbf(o[g][r]);
        }
    __syncthreads();
    {
        size_t ob = (size_t)((chunk * 2 + bhalf) * 2 + hhalf) * 16384;
        #pragma unroll
        for (int it = 0; it < 8; ++it) {
            int off = it * 2048 + t * 8;
            *(us8_t*)&opart[ob + off] = *(const us8_t*)&Ol[off];
        }
    }
    den += __shfl_xor(den, 32, 64);
    if (hi == 0 && hhalf == 0)
        dpart[chunk * 256 + bhalf * 128 + w * 32 + l31] = den;
}

// ---------------- kernel 3: reduce partials + LSTM epilogue -----------------
__global__ __launch_bounds__(256) void k_reduce(
    const unsigned short* __restrict__ opart, const float* __restrict__ dpart,
    const float* __restrict__ pre, const float* __restrict__ c_in,
    float* __restrict__ out)
{
    __shared__ float sred[4];
    int b = blockIdx.x, t = threadIdx.x;

    float ds = dpart[t * 256 + b];
    #pragma unroll
    for (int m = 1; m < 64; m <<= 1) ds += __shfl_xor(ds, m, 64);
    if ((t & 63) == 0) sred[t >> 6] = ds;
    __syncthreads();
    float dtot = fmaxf(sred[0] + sred[1] + sred[2] + sred[3], 1e-30f);

    int bh = b >> 7, br = b & 127;
    int hh = t >> 7, hc = t & 127;
    size_t sb = (size_t)(bh * 2 + hh) * 16384 + br * 128 + hc;
    float n0 = 0.f, n1 = 0.f, n2 = 0.f, n3 = 0.f;
    for (int ck = 0; ck < 256; ck += 4) {
        n0 += bf2f(opart[(size_t)(ck + 0) * 65536 + sb]);
        n1 += bf2f(opart[(size_t)(ck + 1) * 65536 + sb]);
        n2 += bf2f(opart[(size_t)(ck + 2) * 65536 + sb]);
        n3 += bf2f(opart[(size_t)(ck + 3) * 65536 + sb]);
    }
    float num = (n0 + n1) + (n2 + n3);

    float m = tanhf(num / dtot);
    const float* p = pre + b * 1280;
    float fg = sigf(p[t]);
    float ig = sigf(p[256 + t]);
    float og = sigf(p[512 + t]);
    float rg = sigf(p[768 + t]);
    float cn = tanhf(p[1024 + t]);
    float co = c_in[b * 256 + t];
    float ct = fg * co + ig * cn + rg * m;
    float ht = og * tanhf(ct);
    out[b * 256 + t] = ht;
    out[65536 + b * 256 + t] = ct;
}

// ---------------- launch ----------------------------------------------------
extern "C" void kernel_launch(void* const* d_in, const int* in_sizes, int n_in,
                              void* d_out, int out_size, void* d_ws, size_t ws_size,
                              hipStream_t stream)
{
    const float* x    = (const float*)d_in[0];
    const float* h    = (const float*)d_in[1];
    const float* c    = (const float*)d_in[2];
    const float* W1   = (const float*)d_in[3];
    const float* b1   = (const float*)d_in[4];
    const float* W2   = (const float*)d_in[5];
    const float* b2   = (const float*)d_in[6];
    const float* keys = (const float*)d_in[7];
    const float* vals = (const float*)d_in[8];
    int L = in_sizes[7] / 256;

    // 256 chunks, each a multiple of 32 keys
    int TILES = (L + 256 * 32 - 1) / (256 * 32);
    int CH = TILES * 32;

    char* ws = (char*)d_ws;
    unsigned short* qn    = (unsigned short*)(ws + 0);
    unsigned short* xb    = (unsigned short*)(ws + 131072);
    unsigned short* hb    = (unsigned short*)(ws + 262144);
    unsigned short* w1b   = (unsigned short*)(ws + 393216);
    unsigned short* w2b   = (unsigned short*)(ws + 1048576);
    float*          pre   = (float*)(ws + 1703936);
    float*          dpart = (float*)(ws + 3014656);   // 256*256 f32 = 256KB
    unsigned short* opart = (unsigned short*)(ws + 3276800);  // 1024*16384*2B

    k_convert<<<dim3(1024), dim3(256), 0, stream>>>(x, h, W1, W2, qn, xb, hb, w1b, w2b);
    k_gates<<<dim3(80), dim3(256), 0, stream>>>(xb, hb, w1b, w2b, b1, b2, pre);
    k_dnd<<<dim3(1024), dim3(256), 0, stream>>>(keys, vals, qn, opart, dpart, L, CH);
    k_reduce<<<dim3(256), dim3(256), 0, stream>>>(opart, dpart, pre, c, (float*)d_out);

    (void)n_in; (void)out_size; (void)ws_size;
}